// Round 6
// baseline (455.166 us; speedup 1.0000x reference)
//
#include <hip/hip_runtime.h>

// Problem constants (reference: B=16, N=2048, D=64, fp32 in/out)
#define Bb 16
#define Nn 2048
#define Dd 64

typedef __attribute__((ext_vector_type(8))) short s16x8;  // 8 bf16 (A/B frag, 16x16x32)
typedef __attribute__((ext_vector_type(4))) float fx4;    // MFMA accumulator

__device__ __forceinline__ unsigned short f2bf(float f) {
  union { float f; unsigned u; } v; v.f = f;
  unsigned r = v.u + 0x7FFFu + ((v.u >> 16) & 1u);  // round-to-nearest-even
  return (unsigned short)(r >> 16);
}

// ---- prep 1: K fp32 -> bf16 (row-major [B][N][D]) -------------------------
__global__ void k_cvtK(const float* __restrict__ K, unsigned short* __restrict__ Kb) {
  int i = blockIdx.x * 256 + threadIdx.x;
  float4 f = ((const float4*)K)[i];
  ushort4 o;
  o.x = f2bf(f.x); o.y = f2bf(f.y); o.z = f2bf(f.z); o.w = f2bf(f.w);
  ((ushort4*)Kb)[i] = o;
}

// ---- prep 2: V [B][N][D] fp32 -> VT [B][D][N] bf16 ------------------------
__global__ void k_transV(const float* __restrict__ V, unsigned short* __restrict__ VT) {
  __shared__ float tile[32][33];
  int b = blockIdx.z;
  int j0 = blockIdx.x * 32, d0 = blockIdx.y * 32;
  int tx = threadIdx.x, ty = threadIdx.y;  // block (32,8)
  const float* Vb = V + (size_t)b * Nn * Dd;
  unsigned short* Tb = VT + (size_t)b * Dd * Nn;
  for (int r = ty; r < 32; r += 8)
    tile[r][tx] = Vb[(size_t)(j0 + r) * Dd + d0 + tx];
  __syncthreads();
  for (int r = ty; r < 32; r += 8)
    Tb[(size_t)(d0 + r) * Nn + j0 + tx] = f2bf(tile[tx][r]);
}

// ---- main fused attention -------------------------------------------------
// Split-k x4 (4 waves, 16 q rows, wave w owns k in [w*512,(w+1)*512)).
// Sweep 2 is software-pipelined so that NO load is ever issued after an att
// store (vmcnt retires strictly in issue order, so a load-wait drains every
// older store; r5's tail-clustered stores still forced a full drain per tile).
// Per 64-col tile: QK from prefetched K regs -> reload K(t+1) -> softmax +
// stage P in LDS (lgkm domain) -> PV from prefetched V regs -> reload V(t+1)
// -> THEN the tile's 4 nt stores. Loop waits become vmcnt(~12); stores drain
// only at kernel end.
__global__ __launch_bounds__(256) void k_attn(
    const float* __restrict__ Q, const unsigned short* __restrict__ Kbf,
    const unsigned short* __restrict__ VTbf, const float* __restrict__ scale_p,
    float* __restrict__ ctx, float* __restrict__ att) {
  // XCD-aware bijective swizzle: 2048 blocks, 8 XCDs -> each XCD gets a
  // contiguous run of 256 blocks = 2 batches worth of K/V (~1 MB in L2).
  const int id = blockIdx.x;
  const int swz = ((id & 7) << 8) | (id >> 3);
  const int b = swz >> 7;            // batch
  const int q0 = (swz & 127) << 4;   // q-tile base (16 rows)

  const int tid = threadIdx.x;
  const int wave = tid >> 6, lane = tid & 63;
  const int nl = lane & 15, quad = lane >> 4;
  const int qrow = q0 + nl;
  const float c2 = scale_p[0] * 1.44269504088896341f;  // scale * log2(e)

  __shared__ float sm[4][16];
  __shared__ float sl[4][16];
  // 16 KB multi-purpose: per-wave P staging (bf16, XOR-swizzled, 2 KB used of
  // 4 KB/wave) in sweep 2, then O-merge tile at the end (after a barrier).
  __shared__ __align__(16) float obf[4 * 1024];
  char* pbw = (char*)obf + wave * 4096;  // this wave's P staging region
  const int swz8 = (nl & 7) << 4;

  // Q fragment (B operand): B[n=q][k = kt*32 + quad*8 + j], fp32->bf16 inline
  s16x8 qb[2];
  {
    const float* qp = Q + ((size_t)b * Nn + qrow) * Dd + quad * 8;
#pragma unroll
    for (int kt = 0; kt < 2; ++kt) {
      float4 f0 = *(const float4*)(qp + kt * 32);
      float4 f1 = *(const float4*)(qp + kt * 32 + 4);
      s16x8 t;
      t[0] = (short)f2bf(f0.x); t[1] = (short)f2bf(f0.y);
      t[2] = (short)f2bf(f0.z); t[3] = (short)f2bf(f0.w);
      t[4] = (short)f2bf(f1.x); t[5] = (short)f2bf(f1.y);
      t[6] = (short)f2bf(f1.z); t[7] = (short)f2bf(f1.w);
      qb[kt] = t;
    }
  }
  const unsigned short* Kb = Kbf + (size_t)b * Nn * Dd;
  const unsigned short* VTb = VTbf + (size_t)b * Dd * Nn;
  float* attb = att + (size_t)b * Nn * Nn;

  float m = -3.0e38f, l = 0.0f;

  // ---- sweep 1: online max / sum over this wave's 4 k-tiles (no stores) ---
  for (int t = 0; t < 4; ++t) {
    const int k0 = (wave * 4 + t) * 128;
    fx4 s[8];
#pragma unroll
    for (int nt = 0; nt < 8; ++nt) s[nt] = (fx4){0.f, 0.f, 0.f, 0.f};
#pragma unroll
    for (int nt = 0; nt < 8; ++nt) {
      const s16x8* ka =
          (const s16x8*)(Kb + ((size_t)(k0 + nt * 16 + nl)) * Dd + quad * 8);
      s[nt] = __builtin_amdgcn_mfma_f32_16x16x32_bf16(ka[0], qb[0], s[nt], 0, 0, 0);
      s[nt] = __builtin_amdgcn_mfma_f32_16x16x32_bf16(ka[4], qb[1], s[nt], 0, 0, 0);
    }
    // 4 parallel max chains (depth 8)
    float x0 = s[0][0], x1 = s[0][1], x2 = s[0][2], x3 = s[0][3];
#pragma unroll
    for (int nt = 1; nt < 8; ++nt) {
      x0 = fmaxf(x0, s[nt][0]); x1 = fmaxf(x1, s[nt][1]);
      x2 = fmaxf(x2, s[nt][2]); x3 = fmaxf(x3, s[nt][3]);
    }
    float lm = fmaxf(fmaxf(x0, x1), fmaxf(x2, x3));
    float mn = fmaxf(m, lm * c2);
    // 4 parallel sum chains (depth 8)
    float a0 = 0.f, a1 = 0.f, a2 = 0.f, a3 = 0.f;
#pragma unroll
    for (int nt = 0; nt < 8; ++nt) {
      a0 += exp2f(fmaf(s[nt][0], c2, -mn));
      a1 += exp2f(fmaf(s[nt][1], c2, -mn));
      a2 += exp2f(fmaf(s[nt][2], c2, -mn));
      a3 += exp2f(fmaf(s[nt][3], c2, -mn));
    }
    float ls = (a0 + a1) + (a2 + a3);
    l = l * exp2f(m - mn) + ls;
    m = mn;
  }
  // merge the 4 quads (each covered a disjoint k-subset of the same q)
#pragma unroll
  for (int mask = 16; mask <= 32; mask <<= 1) {
    float om = __shfl_xor(m, mask, 64);
    float ol = __shfl_xor(l, mask, 64);
    float mn = fmaxf(m, om);
    l = l * exp2f(m - mn) + ol * exp2f(om - mn);
    m = mn;
  }
  // merge across the 4 waves (disjoint k quarters of the same q rows)
  if (lane < 16) { sm[wave][lane] = m; sl[wave][lane] = l; }
  __syncthreads();
  float rinv;
  {
    float M = sm[0][nl], L = sl[0][nl];
#pragma unroll
    for (int j = 1; j < 4; ++j) {
      float mj = sm[j][nl], lj = sl[j][nl];
      float mn = fmaxf(M, mj);
      L = L * exp2f(M - mn) + lj * exp2f(mj - mn);
      M = mn;
    }
    m = M;
    rinv = 1.0f / L;
  }

  // ---- sweep 2: pipelined QK -> softmax -> PV -> tail stores --------------
  fx4 o[4];
#pragma unroll
  for (int d = 0; d < 4; ++d) o[d] = (fx4){0.f, 0.f, 0.f, 0.f};

  s16x8 kr[8], vr[8];
  {
    const int k0 = wave * 512;
#pragma unroll
    for (int nt = 0; nt < 4; ++nt) {
      const s16x8* ka =
          (const s16x8*)(Kb + ((size_t)(k0 + nt * 16 + nl)) * Dd + quad * 8);
      kr[2 * nt] = ka[0]; kr[2 * nt + 1] = ka[4];
    }
#pragma unroll
    for (int kt = 0; kt < 2; ++kt)
#pragma unroll
      for (int ntd = 0; ntd < 4; ++ntd)
        vr[kt * 4 + ntd] = *(const s16x8*)(VTb + ((size_t)(ntd * 16 + nl)) * Nn +
                                           k0 + kt * 32 + quad * 8);
  }

  for (int t = 0; t < 8; ++t) {
    const int k0 = wave * 512 + t * 64;
    const int k0n = wave * 512 + ((t + 1) & 7) * 64;  // wraps at t=7 (harmless)
    // QK from prefetched K regs
    fx4 s[4];
#pragma unroll
    for (int nt = 0; nt < 4; ++nt) {
      s[nt] = (fx4){0.f, 0.f, 0.f, 0.f};
      s[nt] = __builtin_amdgcn_mfma_f32_16x16x32_bf16(kr[2 * nt], qb[0], s[nt], 0, 0, 0);
      s[nt] = __builtin_amdgcn_mfma_f32_16x16x32_bf16(kr[2 * nt + 1], qb[1], s[nt], 0, 0, 0);
    }
    // reload K for next tile (WAR on kr: issues after QK consumed them,
    // and BEFORE this tile's stores -> next QK wait never drains stores)
#pragma unroll
    for (int nt = 0; nt < 4; ++nt) {
      const s16x8* ka =
          (const s16x8*)(Kb + ((size_t)(k0n + nt * 16 + nl)) * Dd + quad * 8);
      kr[2 * nt] = ka[0]; kr[2 * nt + 1] = ka[4];
    }
    // softmax normalize in place (fp32 kept for the att store), stage bf16 P
#pragma unroll
    for (int nt = 0; nt < 4; ++nt) {
#pragma unroll
      for (int r = 0; r < 4; ++r)
        s[nt][r] = exp2f(fmaf(s[nt][r], c2, -m)) * rinv;
      unsigned long long pk =
          (unsigned long long)f2bf(s[nt][0]) |
          ((unsigned long long)f2bf(s[nt][1]) << 16) |
          ((unsigned long long)f2bf(s[nt][2]) << 32) |
          ((unsigned long long)f2bf(s[nt][3]) << 48);
      // row nl (128 B stride), col bytes = nt*32 + quad*8, XOR-swizzled
      *(unsigned long long*)(pbw + nl * 128 + ((nt * 32 + quad * 8) ^ swz8)) = pk;
    }
    // PV from LDS P + prefetched V regs (pure lgkm domain — no vmem wait)
#pragma unroll
    for (int kt = 0; kt < 2; ++kt) {
      s16x8 pa =
          *(const s16x8*)(pbw + nl * 128 + ((kt * 64 + quad * 16) ^ swz8));
#pragma unroll
      for (int ntd = 0; ntd < 4; ++ntd)
        o[ntd] = __builtin_amdgcn_mfma_f32_16x16x32_bf16(pa, vr[kt * 4 + ntd],
                                                         o[ntd], 0, 0, 0);
    }
    // reload V for next tile (WAR on vr; before the stores)
#pragma unroll
    for (int kt = 0; kt < 2; ++kt)
#pragma unroll
      for (int ntd = 0; ntd < 4; ++ntd)
        vr[kt * 4 + ntd] = *(const s16x8*)(VTb + ((size_t)(ntd * 16 + nl)) * Nn +
                                           k0n + kt * 32 + quad * 8);
    // tail: this tile's att stores. sched_barrier fences keep all loads
    // above the stores so no later load-wait ever queues behind them.
    __builtin_amdgcn_sched_barrier(0);
#pragma unroll
    for (int nt = 0; nt < 4; ++nt)
      __builtin_nontemporal_store(
          s[nt], (fx4*)(attb + (size_t)qrow * Nn + k0 + nt * 16 + quad * 4));
    __builtin_amdgcn_sched_barrier(0);
  }

  // ---- merge partial O across the 4 waves, write ctx ----------------------
  // barrier first: merge regions overlap other waves' P staging (r5 raced).
  __syncthreads();
  {
    float* myob = obf + wave * 1024;
#pragma unroll
    for (int ntd = 0; ntd < 4; ++ntd)
#pragma unroll
      for (int r = 0; r < 4; ++r) {
        const int row = quad * 4 + r;
        const int unit = ntd * 4 + (nl >> 2);
        const int su = unit ^ (row & 7);
        myob[row * 64 + su * 4 + (nl & 3)] = o[ntd][r];
      }
  }
  __syncthreads();
  {
    const int row = tid >> 4;         // 0..15
    const int un = tid & 15;          // 16B unit
    const int su = un ^ (row & 7);
    fx4 a = *(const fx4*)&obf[row * 64 + su * 4];
#pragma unroll
    for (int j = 1; j < 4; ++j) {
      fx4 tt = *(const fx4*)&obf[j * 1024 + row * 64 + su * 4];
      a[0] += tt[0]; a[1] += tt[1]; a[2] += tt[2]; a[3] += tt[3];
    }
    *(fx4*)(ctx + ((size_t)b * Nn + q0 + row) * Dd + un * 4) = a;
  }
}

extern "C" void kernel_launch(void* const* d_in, const int* in_sizes, int n_in,
                              void* d_out, int out_size, void* d_ws, size_t ws_size,
                              hipStream_t stream) {
  const float* q = (const float*)d_in[0];
  const float* k = (const float*)d_in[1];
  const float* v = (const float*)d_in[2];
  const float* scale = (const float*)d_in[3];

  float* ctx = (float*)d_out;                       // [16,2048,64]
  float* att = ctx + (size_t)Bb * Nn * Dd;          // [16,2048,2048]

  // workspace: Kbf (4 MB bf16) + VTbf (4 MB bf16); rebuilt every call
  unsigned short* Kbf = (unsigned short*)d_ws;
  unsigned short* VTbf = Kbf + (size_t)Bb * Nn * Dd;

  hipLaunchKernelGGL(k_cvtK, dim3((Bb * Nn * Dd) / (256 * 4)), dim3(256), 0, stream,
                     k, Kbf);
  hipLaunchKernelGGL(k_transV, dim3(Nn / 32, Dd / 32, Bb), dim3(32, 8), 0, stream,
                     v, VTbf);
  hipLaunchKernelGGL(k_attn, dim3(Bb * Nn / 16), dim3(256), 0, stream,
                     q, Kbf, VTbf, scale, ctx, att);
}

// Round 7
// 446.173 us; speedup vs baseline: 1.0202x; 1.0202x over previous
//
#include <hip/hip_runtime.h>

// Problem constants (reference: B=16, N=2048, D=64, fp32 in/out)
#define Bb 16
#define Nn 2048
#define Dd 64

typedef __attribute__((ext_vector_type(8))) short s16x8;  // 8 bf16 (A/B frag, 16x16x32)
typedef __attribute__((ext_vector_type(4))) float fx4;    // MFMA accumulator

__device__ __forceinline__ unsigned short f2bf(float f) {
  union { float f; unsigned u; } v; v.f = f;
  unsigned r = v.u + 0x7FFFu + ((v.u >> 16) & 1u);  // round-to-nearest-even
  return (unsigned short)(r >> 16);
}

// ---- prep 1: K fp32 -> bf16 (row-major [B][N][D]) -------------------------
__global__ void k_cvtK(const float* __restrict__ K, unsigned short* __restrict__ Kb) {
  int i = blockIdx.x * 256 + threadIdx.x;
  float4 f = ((const float4*)K)[i];
  ushort4 o;
  o.x = f2bf(f.x); o.y = f2bf(f.y); o.z = f2bf(f.z); o.w = f2bf(f.w);
  ((ushort4*)Kb)[i] = o;
}

// ---- prep 2: V [B][N][D] fp32 -> VT [B][D][N] bf16 ------------------------
__global__ void k_transV(const float* __restrict__ V, unsigned short* __restrict__ VT) {
  __shared__ float tile[32][33];
  int b = blockIdx.z;
  int j0 = blockIdx.x * 32, d0 = blockIdx.y * 32;
  int tx = threadIdx.x, ty = threadIdx.y;  // block (32,8)
  const float* Vb = V + (size_t)b * Nn * Dd;
  unsigned short* Tb = VT + (size_t)b * Dd * Nn;
  for (int r = ty; r < 32; r += 8)
    tile[r][tx] = Vb[(size_t)(j0 + r) * Dd + d0 + tx];
  __syncthreads();
  for (int r = ty; r < 32; r += 8)
    Tb[(size_t)(d0 + r) * Nn + j0 + tx] = f2bf(tile[tx][r]);
}

// ---- main fused attention -------------------------------------------------
// Split-k x4 (4 waves, 16 q rows, wave w owns k in [w*512,(w+1)*512)).
// Pipelined sweep 2 (QK from prefetched K regs -> reload K(t+1) -> softmax +
// LDS P staging -> PV from prefetched V regs -> reload V(t+1) -> tail stores)
// so no load is issued after a store it could wait behind.
// A/B vs r5: att stores are PLAIN (not nontemporal). nt bypassed L2
// write-combining -> 16x 64 B granules per store instr -> partial-sector HBM
// writes (WRITE_SIZE inflated 1.1-1.2x, write BW capped ~1.4 TB/s). Normal
// write-allocate stores merge to full 128 B lines in L2 (copy ubench shows
// ~3.15 TB/s write is attainable). FETCH has been ~8 MB all along, so the
// stream cannot thrash anything that matters.
__global__ __launch_bounds__(256) void k_attn(
    const float* __restrict__ Q, const unsigned short* __restrict__ Kbf,
    const unsigned short* __restrict__ VTbf, const float* __restrict__ scale_p,
    float* __restrict__ ctx, float* __restrict__ att) {
  // XCD-aware bijective swizzle: 2048 blocks, 8 XCDs -> each XCD gets a
  // contiguous run of 256 blocks = 2 batches worth of K/V (~1 MB in L2).
  const int id = blockIdx.x;
  const int swz = ((id & 7) << 8) | (id >> 3);
  const int b = swz >> 7;            // batch
  const int q0 = (swz & 127) << 4;   // q-tile base (16 rows)

  const int tid = threadIdx.x;
  const int wave = tid >> 6, lane = tid & 63;
  const int nl = lane & 15, quad = lane >> 4;
  const int qrow = q0 + nl;
  const float c2 = scale_p[0] * 1.44269504088896341f;  // scale * log2(e)

  __shared__ float sm[4][16];
  __shared__ float sl[4][16];
  // 16 KB multi-purpose: per-wave P staging (bf16, XOR-swizzled, 2 KB used of
  // 4 KB/wave) in sweep 2, then O-merge tile at the end (after a barrier).
  __shared__ __align__(16) float obf[4 * 1024];
  char* pbw = (char*)obf + wave * 4096;  // this wave's P staging region
  const int swz8 = (nl & 7) << 4;

  // Q fragment (B operand): B[n=q][k = kt*32 + quad*8 + j], fp32->bf16 inline
  s16x8 qb[2];
  {
    const float* qp = Q + ((size_t)b * Nn + qrow) * Dd + quad * 8;
#pragma unroll
    for (int kt = 0; kt < 2; ++kt) {
      float4 f0 = *(const float4*)(qp + kt * 32);
      float4 f1 = *(const float4*)(qp + kt * 32 + 4);
      s16x8 t;
      t[0] = (short)f2bf(f0.x); t[1] = (short)f2bf(f0.y);
      t[2] = (short)f2bf(f0.z); t[3] = (short)f2bf(f0.w);
      t[4] = (short)f2bf(f1.x); t[5] = (short)f2bf(f1.y);
      t[6] = (short)f2bf(f1.z); t[7] = (short)f2bf(f1.w);
      qb[kt] = t;
    }
  }
  const unsigned short* Kb = Kbf + (size_t)b * Nn * Dd;
  const unsigned short* VTb = VTbf + (size_t)b * Dd * Nn;
  float* attb = att + (size_t)b * Nn * Nn;

  float m = -3.0e38f, l = 0.0f;

  // ---- sweep 1: online max / sum over this wave's 4 k-tiles (no stores) ---
  for (int t = 0; t < 4; ++t) {
    const int k0 = (wave * 4 + t) * 128;
    fx4 s[8];
#pragma unroll
    for (int nt = 0; nt < 8; ++nt) s[nt] = (fx4){0.f, 0.f, 0.f, 0.f};
#pragma unroll
    for (int nt = 0; nt < 8; ++nt) {
      const s16x8* ka =
          (const s16x8*)(Kb + ((size_t)(k0 + nt * 16 + nl)) * Dd + quad * 8);
      s[nt] = __builtin_amdgcn_mfma_f32_16x16x32_bf16(ka[0], qb[0], s[nt], 0, 0, 0);
      s[nt] = __builtin_amdgcn_mfma_f32_16x16x32_bf16(ka[4], qb[1], s[nt], 0, 0, 0);
    }
    // 4 parallel max chains (depth 8)
    float x0 = s[0][0], x1 = s[0][1], x2 = s[0][2], x3 = s[0][3];
#pragma unroll
    for (int nt = 1; nt < 8; ++nt) {
      x0 = fmaxf(x0, s[nt][0]); x1 = fmaxf(x1, s[nt][1]);
      x2 = fmaxf(x2, s[nt][2]); x3 = fmaxf(x3, s[nt][3]);
    }
    float lm = fmaxf(fmaxf(x0, x1), fmaxf(x2, x3));
    float mn = fmaxf(m, lm * c2);
    // 4 parallel sum chains (depth 8)
    float a0 = 0.f, a1 = 0.f, a2 = 0.f, a3 = 0.f;
#pragma unroll
    for (int nt = 0; nt < 8; ++nt) {
      a0 += exp2f(fmaf(s[nt][0], c2, -mn));
      a1 += exp2f(fmaf(s[nt][1], c2, -mn));
      a2 += exp2f(fmaf(s[nt][2], c2, -mn));
      a3 += exp2f(fmaf(s[nt][3], c2, -mn));
    }
    float ls = (a0 + a1) + (a2 + a3);
    l = l * exp2f(m - mn) + ls;
    m = mn;
  }
  // merge the 4 quads (each covered a disjoint k-subset of the same q)
#pragma unroll
  for (int mask = 16; mask <= 32; mask <<= 1) {
    float om = __shfl_xor(m, mask, 64);
    float ol = __shfl_xor(l, mask, 64);
    float mn = fmaxf(m, om);
    l = l * exp2f(m - mn) + ol * exp2f(om - mn);
    m = mn;
  }
  // merge across the 4 waves (disjoint k quarters of the same q rows)
  if (lane < 16) { sm[wave][lane] = m; sl[wave][lane] = l; }
  __syncthreads();
  float rinv;
  {
    float M = sm[0][nl], L = sl[0][nl];
#pragma unroll
    for (int j = 1; j < 4; ++j) {
      float mj = sm[j][nl], lj = sl[j][nl];
      float mn = fmaxf(M, mj);
      L = L * exp2f(M - mn) + lj * exp2f(mj - mn);
      M = mn;
    }
    m = M;
    rinv = 1.0f / L;
  }

  // ---- sweep 2: pipelined QK -> softmax -> PV -> tail stores --------------
  fx4 o[4];
#pragma unroll
  for (int d = 0; d < 4; ++d) o[d] = (fx4){0.f, 0.f, 0.f, 0.f};

  s16x8 kr[8], vr[8];
  {
    const int k0 = wave * 512;
#pragma unroll
    for (int nt = 0; nt < 4; ++nt) {
      const s16x8* ka =
          (const s16x8*)(Kb + ((size_t)(k0 + nt * 16 + nl)) * Dd + quad * 8);
      kr[2 * nt] = ka[0]; kr[2 * nt + 1] = ka[4];
    }
#pragma unroll
    for (int kt = 0; kt < 2; ++kt)
#pragma unroll
      for (int ntd = 0; ntd < 4; ++ntd)
        vr[kt * 4 + ntd] = *(const s16x8*)(VTb + ((size_t)(ntd * 16 + nl)) * Nn +
                                           k0 + kt * 32 + quad * 8);
  }

  for (int t = 0; t < 8; ++t) {
    const int k0 = wave * 512 + t * 64;
    const int k0n = wave * 512 + ((t + 1) & 7) * 64;  // wraps at t=7 (harmless)
    // QK from prefetched K regs
    fx4 s[4];
#pragma unroll
    for (int nt = 0; nt < 4; ++nt) {
      s[nt] = (fx4){0.f, 0.f, 0.f, 0.f};
      s[nt] = __builtin_amdgcn_mfma_f32_16x16x32_bf16(kr[2 * nt], qb[0], s[nt], 0, 0, 0);
      s[nt] = __builtin_amdgcn_mfma_f32_16x16x32_bf16(kr[2 * nt + 1], qb[1], s[nt], 0, 0, 0);
    }
    // reload K for next tile (WAR on kr: issues after QK consumed them,
    // and BEFORE this tile's stores -> next QK wait never drains stores)
#pragma unroll
    for (int nt = 0; nt < 4; ++nt) {
      const s16x8* ka =
          (const s16x8*)(Kb + ((size_t)(k0n + nt * 16 + nl)) * Dd + quad * 8);
      kr[2 * nt] = ka[0]; kr[2 * nt + 1] = ka[4];
    }
    // softmax normalize in place (fp32 kept for the att store), stage bf16 P
#pragma unroll
    for (int nt = 0; nt < 4; ++nt) {
#pragma unroll
      for (int r = 0; r < 4; ++r)
        s[nt][r] = exp2f(fmaf(s[nt][r], c2, -m)) * rinv;
      unsigned long long pk =
          (unsigned long long)f2bf(s[nt][0]) |
          ((unsigned long long)f2bf(s[nt][1]) << 16) |
          ((unsigned long long)f2bf(s[nt][2]) << 32) |
          ((unsigned long long)f2bf(s[nt][3]) << 48);
      // row nl (128 B stride), col bytes = nt*32 + quad*8, XOR-swizzled
      *(unsigned long long*)(pbw + nl * 128 + ((nt * 32 + quad * 8) ^ swz8)) = pk;
    }
    // PV from LDS P + prefetched V regs (pure lgkm domain — no vmem wait)
#pragma unroll
    for (int kt = 0; kt < 2; ++kt) {
      s16x8 pa =
          *(const s16x8*)(pbw + nl * 128 + ((kt * 64 + quad * 16) ^ swz8));
#pragma unroll
      for (int ntd = 0; ntd < 4; ++ntd)
        o[ntd] = __builtin_amdgcn_mfma_f32_16x16x32_bf16(pa, vr[kt * 4 + ntd],
                                                         o[ntd], 0, 0, 0);
    }
    // reload V for next tile (WAR on vr; before the stores)
#pragma unroll
    for (int kt = 0; kt < 2; ++kt)
#pragma unroll
      for (int ntd = 0; ntd < 4; ++ntd)
        vr[kt * 4 + ntd] = *(const s16x8*)(VTb + ((size_t)(ntd * 16 + nl)) * Nn +
                                           k0n + kt * 32 + quad * 8);
    // tail: this tile's att stores (plain, write-allocate -> L2 merges the
    // four 64 B row-chunks into full lines). Fence keeps all loads above.
    __builtin_amdgcn_sched_barrier(0);
#pragma unroll
    for (int nt = 0; nt < 4; ++nt)
      *(fx4*)(attb + (size_t)qrow * Nn + k0 + nt * 16 + quad * 4) = s[nt];
  }

  // ---- merge partial O across the 4 waves, write ctx ----------------------
  {
    float* myob = obf + wave * 1024;
#pragma unroll
    for (int ntd = 0; ntd < 4; ++ntd)
#pragma unroll
      for (int r = 0; r < 4; ++r) {
        const int row = quad * 4 + r;
        const int unit = ntd * 4 + (nl >> 2);
        const int su = unit ^ (row & 7);
        myob[row * 64 + su * 4 + (nl & 3)] = o[ntd][r];
      }
  }
  __syncthreads();
  {
    const int row = tid >> 4;         // 0..15
    const int un = tid & 15;          // 16B unit
    const int su = un ^ (row & 7);
    fx4 a = *(const fx4*)&obf[row * 64 + su * 4];
#pragma unroll
    for (int j = 1; j < 4; ++j) {
      fx4 tt = *(const fx4*)&obf[j * 1024 + row * 64 + su * 4];
      a[0] += tt[0]; a[1] += tt[1]; a[2] += tt[2]; a[3] += tt[3];
    }
    *(fx4*)(ctx + ((size_t)b * Nn + q0 + row) * Dd + un * 4) = a;
  }
}

extern "C" void kernel_launch(void* const* d_in, const int* in_sizes, int n_in,
                              void* d_out, int out_size, void* d_ws, size_t ws_size,
                              hipStream_t stream) {
  const float* q = (const float*)d_in[0];
  const float* k = (const float*)d_in[1];
  const float* v = (const float*)d_in[2];
  const float* scale = (const float*)d_in[3];

  float* ctx = (float*)d_out;                       // [16,2048,64]
  float* att = ctx + (size_t)Bb * Nn * Dd;          // [16,2048,2048]

  // workspace: Kbf (4 MB bf16) + VTbf (4 MB bf16); rebuilt every call
  unsigned short* Kbf = (unsigned short*)d_ws;
  unsigned short* VTbf = Kbf + (size_t)Bb * Nn * Dd;

  hipLaunchKernelGGL(k_cvtK, dim3((Bb * Nn * Dd) / (256 * 4)), dim3(256), 0, stream,
                     k, Kbf);
  hipLaunchKernelGGL(k_transV, dim3(Nn / 32, Dd / 32, Bb), dim3(32, 8), 0, stream,
                     v, VTbf);
  hipLaunchKernelGGL(k_attn, dim3(Bb * Nn / 16), dim3(256), 0, stream,
                     q, Kbf, VTbf, scale, ctx, att);
}